// Round 6
// baseline (333.025 us; speedup 1.0000x reference)
//
#include <hip/hip_runtime.h>
#include <hip/hip_bf16.h>

#define NN 4096
#define DD 512
#define HH 8
#define DH 64
#define BN 8192        // total rows (B*N)
#define PAIRS 16       // B*H

typedef unsigned int uint32;
typedef __attribute__((ext_vector_type(8))) short short8;
typedef __attribute__((ext_vector_type(4))) float f32x4;

__device__ __forceinline__ float blo(uint32 u) {
    union { uint32 i; float f; } c; c.i = u << 16; return c.f;
}
__device__ __forceinline__ unsigned short f2b(float x) {   // round-half-up to bf16
    union { float f; uint32 u; } c; c.f = x;
    return (unsigned short)((c.u + 0x8000u) >> 16);
}
__device__ __forceinline__ uint32 pack2(float lo, float hi) {
    return (uint32)f2b(lo) | ((uint32)f2b(hi) << 16);
}
__device__ __forceinline__ uint32 cvtpk(float lo, float hi) {  // packed bf16 pair, RNE
    uint32 r;
    asm("v_cvt_pk_bf16_f32 %0, %1, %2" : "=v"(r) : "v"(lo), "v"(hi));
    return r;
}
// softmax scale (1/8 * log2e) pre-folded into Q by qkv_gemm. No clamp needed.
__device__ __forceinline__ float expsc(float s) {
    return __builtin_amdgcn_exp2f(s);
}
#define QSCALE 0.18033688011112042f   // log2(e)/8

// async global->LDS, 16B per lane; LDS dest is wave-uniform base + lane*16
__device__ __forceinline__ void gload16(const void* g, void* l) {
    __builtin_amdgcn_global_load_lds(
        (const __attribute__((address_space(1))) void*)g,
        (__attribute__((address_space(3))) void*)l, 16, 0, 0);
}

// ---------------------------------------------------------------------------
// Kernel 0: dtype probe.
// ---------------------------------------------------------------------------
__global__ void detect_dtype(const uint32* __restrict__ xw, uint32* __restrict__ flag) {
    __shared__ int cnt;
    if (threadIdx.x == 0) cnt = 0;
    __syncthreads();
    int c = 0;
    for (int i = threadIdx.x; i < 1024; i += 64) {
        uint32 e = (xw[i] >> 7) & 0xFFu;
        if (e >= 110u && e <= 135u) c++;
    }
    atomicAdd(&cnt, c);
    __syncthreads();
    if (threadIdx.x == 0) *flag = (cnt < 512) ? 1u : 0u;
}

// ---------------------------------------------------------------------------
// Convert kernels (unchanged).
// ---------------------------------------------------------------------------
__global__ __launch_bounds__(256) void conv_x(const void* __restrict__ src,
                                              unsigned short* __restrict__ dst,
                                              const uint32* __restrict__ flagp) {
    int i0 = (blockIdx.x * 256 + threadIdx.x) * 8;
    if (*flagp) {
        const float4* s = (const float4*)src;
        float4 a = s[i0 >> 2], b = s[(i0 >> 2) + 1];
        uint4 o;
        o.x = pack2(a.x, a.y); o.y = pack2(a.z, a.w);
        o.z = pack2(b.x, b.y); o.w = pack2(b.z, b.w);
        *(uint4*)(dst + i0) = o;
    } else {
        *(uint4*)(dst + i0) = ((const uint4*)src)[i0 >> 3];
    }
}

__global__ __launch_bounds__(256) void conv_w(const void* s0, const void* s1,
                                              const void* s2, const void* s3,
                                              unsigned short* __restrict__ dst,
                                              const uint32* __restrict__ flagp) {
    int seg = blockIdx.x >> 7;
    const void* src = (seg == 0) ? s0 : (seg == 1) ? s1 : (seg == 2) ? s2 : s3;
    unsigned short* d = dst + (size_t)seg * DD * DD;
    int i0 = ((blockIdx.x & 127) * 256 + threadIdx.x) * 8;
    if (*flagp) {
        const float4* s = (const float4*)src;
        float4 a = s[i0 >> 2], b = s[(i0 >> 2) + 1];
        uint4 o;
        o.x = pack2(a.x, a.y); o.y = pack2(a.z, a.w);
        o.z = pack2(b.x, b.y); o.w = pack2(b.z, b.w);
        *(uint4*)(d + i0) = o;
    } else {
        *(uint4*)(d + i0) = ((const uint4*)src)[i0 >> 3];
    }
}

__global__ __launch_bounds__(256) void conv_b(const void* s0, const void* s1,
                                              const void* s2, const void* s3,
                                              float* __restrict__ dst,
                                              const uint32* __restrict__ flagp) {
    const void* sl[4] = { s0, s1, s2, s3 };
    int fp32mode = (int)*flagp;
    #pragma unroll
    for (int m = 0; m < 4; ++m) {
        #pragma unroll
        for (int j = 0; j < 2; ++j) {
            int i = threadIdx.x * 2 + j;
            float v;
            if (fp32mode) v = ((const float*)sl[m])[i];
            else {
                union { uint32 u; float f; } c;
                c.u = ((uint32)((const unsigned short*)sl[m])[i]) << 16;
                v = c.f;
            }
            dst[m * DD + i] = v;
        }
    }
}

// ---------------------------------------------------------------------------
// QKV projection GEMM (unchanged this round): m97-style staging, linear LDS,
// global_load_lds. Q pre-scaled by log2(e)/8.
// ---------------------------------------------------------------------------
__global__ __launch_bounds__(256) void qkv_gemm(
    const unsigned short* __restrict__ xb,
    const unsigned short* __restrict__ wsb,
    const float* __restrict__ bsf,
    unsigned short* __restrict__ Qb, unsigned short* __restrict__ Kb,
    unsigned short* __restrict__ VTg)
{
    __shared__ unsigned short As[128 * 32];
    __shared__ unsigned short Bs[128 * 32];
    const int tid = threadIdx.x;
    const int mat = blockIdx.x >> 8;
    const int rem = blockIdx.x & 255;
    const int nt = rem >> 6, mt = rem & 63;
    const int m0 = mt * 128, n0 = nt * 128;
    const int w = tid >> 6, lane = tid & 63, quad = lane >> 4, col = lane & 15;
    const int wr = w >> 1, wc = w & 1;
    const unsigned short* wm = wsb + (size_t)mat * DD * DD;
    const bool qk = (mat < 2);

    f32x4 acc[4][4];
    #pragma unroll
    for (int i = 0; i < 4; ++i)
        #pragma unroll
        for (int j = 0; j < 4; ++j)
            acc[i][j] = (f32x4){0.f, 0.f, 0.f, 0.f};

    for (int kt = 0; kt < 16; ++kt) {
        int k0 = kt * 32;
        __syncthreads();
        #pragma unroll
        for (int it = 0; it < 2; ++it) {
            int idx = tid + it * 256;
            int row = idx >> 2, c4 = idx & 3;
            unsigned short* lA = &As[(size_t)(it * 256 + w * 64) * 8];
            unsigned short* lB = &Bs[(size_t)(it * 256 + w * 64) * 8];
            gload16(xb + (size_t)(m0 + row) * DD + k0 + c4 * 8, lA);
            gload16(wm + (size_t)(n0 + row) * DD + k0 + c4 * 8, lB);
        }
        __syncthreads();
        if (qk) {
            short8 wf[4], xf[4];
            #pragma unroll
            for (int i = 0; i < 4; ++i)
                wf[i] = *(const short8*)&Bs[(wr * 64 + i * 16 + col) * 32 + quad * 8];
            #pragma unroll
            for (int j = 0; j < 4; ++j)
                xf[j] = *(const short8*)&As[(wc * 64 + j * 16 + col) * 32 + quad * 8];
            #pragma unroll
            for (int i = 0; i < 4; ++i)
                #pragma unroll
                for (int j = 0; j < 4; ++j)
                    acc[i][j] = __builtin_amdgcn_mfma_f32_16x16x32_bf16(
                        wf[i], xf[j], acc[i][j], 0, 0, 0);
        } else {
            short8 xf[4], wf[4];
            #pragma unroll
            for (int i = 0; i < 4; ++i)
                xf[i] = *(const short8*)&As[(wr * 64 + i * 16 + col) * 32 + quad * 8];
            #pragma unroll
            for (int j = 0; j < 4; ++j)
                wf[j] = *(const short8*)&Bs[(wc * 64 + j * 16 + col) * 32 + quad * 8];
            #pragma unroll
            for (int i = 0; i < 4; ++i)
                #pragma unroll
                for (int j = 0; j < 4; ++j)
                    acc[i][j] = __builtin_amdgcn_mfma_f32_16x16x32_bf16(
                        xf[i], wf[j], acc[i][j], 0, 0, 0);
        }
    }

    if (qk) {
        unsigned short* Om = (mat == 0) ? Qb : Kb;
        const float qs = (mat == 0) ? QSCALE : 1.0f;
        #pragma unroll
        for (int i = 0; i < 4; ++i) {
            int e0 = n0 + wr * 64 + i * 16 + quad * 4;
            float4 bj = *(const float4*)(bsf + mat * DD + e0);
            int h = e0 >> 6, jj0 = e0 & 63;
            #pragma unroll
            for (int j = 0; j < 4; ++j) {
                int g = m0 + wc * 64 + j * 16 + col;
                int b = g >> 12, n = g & (NN - 1);
                uint32 lo = pack2((acc[i][j][0] + bj.x) * qs, (acc[i][j][1] + bj.y) * qs);
                uint32 hi = pack2((acc[i][j][2] + bj.z) * qs, (acc[i][j][3] + bj.w) * qs);
                uint2 v; v.x = lo; v.y = hi;
                *(uint2*)(Om + ((size_t)((b << 3) + h) * NN + n) * DH + jj0) = v;
            }
        }
    } else {
        #pragma unroll
        for (int j = 0; j < 4; ++j) {
            int e = n0 + wc * 64 + j * 16 + col;
            float bj = bsf[2 * DD + e];
            int h = e >> 6, jj = e & 63;
            #pragma unroll
            for (int i = 0; i < 4; ++i) {
                int g0 = m0 + wr * 64 + i * 16 + quad * 4;
                int b = g0 >> 12, n = g0 & (NN - 1);
                uint32 lo = pack2(acc[i][j][0] + bj, acc[i][j][1] + bj);
                uint32 hi = pack2(acc[i][j][2] + bj, acc[i][j][3] + bj);
                uint2 v; v.x = lo; v.y = hi;
                *(uint2*)(VTg + ((size_t)((b << 3) + h) * DH + jj) * NN + n) = v;
            }
        }
    }
}

// ---------------------------------------------------------------------------
// MFMA flash attention v7 = v6 + split-K over keys (2 splits of 2048 keys).
// QBLK stays 128 (round-3 lesson: never shrink the q-tile that amortizes the
// sweep); grid doubles to 1024 = 4 blocks/CU = 32 waves/CU. Softmax has no
// running max (scores bounded, exp2 direct), so partials combine by simple
// addition: store unnormalized fp32 accO + fp32 lsum per split.
// ---------------------------------------------------------------------------
__global__ __launch_bounds__(512, 8) void attn_mfma(
    const unsigned short* __restrict__ Qb,
    const unsigned short* __restrict__ Kb,
    const unsigned short* __restrict__ VTg,
    float* __restrict__ Op0, float* __restrict__ Op1,
    float* __restrict__ lpart)
{
    __shared__ unsigned short Kt[2][64 * 72];    // [key][dim],  pad 64->72
    __shared__ unsigned short Vt[2][64 * 72];    // [dim][key],  pad 64->72

    const int tid  = threadIdx.x;
    const int w    = tid >> 6;
    const int lane = tid & 63;
    const int quad = lane >> 4;
    const int col  = lane & 15;
    const int pair  = blockIdx.x >> 6;
    const int split = (blockIdx.x >> 5) & 1;
    const int chunk = blockIdx.x & 31;
    const size_t base = (size_t)pair * NN;
    const int n0 = chunk * 128;
    const int qbase = w * 16;
    const int k0t = split * 32;          // first 64-key tile of this split
    const int kend = k0t + 32;

    // Q A-fragments for this wave's 16 rows: lane&15 = qrow, regs = dim
    short8 qf[2];
    #pragma unroll
    for (int kk = 0; kk < 2; ++kk)
        qf[kk] = *(const short8*)(Qb +
            (base + n0 + qbase + col) * DH + kk * 32 + quad * 8);

    f32x4 accO[4];
    #pragma unroll
    for (int tc = 0; tc < 4; ++tc) accO[tc] = (f32x4){0.f, 0.f, 0.f, 0.f};
    float lsum = 0.f;

    const int skey = tid >> 3;      // 0..63 (key for K stage, dim for V stage)
    const int sc8  = (tid & 7) * 8;
    const unsigned short* Kg = Kb + base * DH;
    const unsigned short* Vg = VTg + (size_t)pair * DH * NN;

    // prologue: tile k0t -> LDS buf0; tile k0t+1 -> regs
    uint4 kreg = *(const uint4*)(Kg + (size_t)(k0t * 64 + skey) * DH + sc8);
    uint4 vreg = *(const uint4*)(Vg + (size_t)skey * NN + k0t * 64 + sc8);
    *(uint4*)&Kt[0][skey * 72 + sc8] = kreg;
    *(uint4*)&Vt[0][skey * 72 + sc8] = vreg;
    kreg = *(const uint4*)(Kg + (size_t)((k0t + 1) * 64 + skey) * DH + sc8);
    vreg = *(const uint4*)(Vg + (size_t)skey * NN + (k0t + 1) * 64 + sc8);
    __syncthreads();

    for (int kt = k0t; kt < kend; ++kt) {
        const int buf = kt & 1;
        if (kt + 1 < kend) {
            // stage next tile into the other buffer; prefetch tile kt+2
            *(uint4*)&Kt[buf ^ 1][skey * 72 + sc8] = kreg;
            *(uint4*)&Vt[buf ^ 1][skey * 72 + sc8] = vreg;
            int tn = (kt + 2 < kend) ? kt + 2 : k0t;   // clamp (dummy, cached)
            kreg = *(const uint4*)(Kg + (size_t)(tn * 64 + skey) * DH + sc8);
            vreg = *(const uint4*)(Vg + (size_t)skey * NN + tn * 64 + sc8);
        }
        const unsigned short* Kc = &Kt[buf][0];
        const unsigned short* Vc = &Vt[buf][0];

        // per 32-key half: S^T via MFMA (2 tiles interleaved), exp, permlane
        short8 pf[2];
        #pragma unroll
        for (int half = 0; half < 2; ++half) {
            f32x4 s0 = (f32x4){0.f, 0.f, 0.f, 0.f};
            f32x4 s1 = (f32x4){0.f, 0.f, 0.f, 0.f};
            __builtin_amdgcn_s_setprio(1);
            #pragma unroll
            for (int kk = 0; kk < 2; ++kk) {
                short8 kf0 = *(const short8*)&Kc[((half * 2 + 0) * 16 + col) * 72 + kk * 32 + quad * 8];
                short8 kf1 = *(const short8*)&Kc[((half * 2 + 1) * 16 + col) * 72 + kk * 32 + quad * 8];
                s0 = __builtin_amdgcn_mfma_f32_16x16x32_bf16(kf0, qf[kk], s0, 0, 0, 0);
                s1 = __builtin_amdgcn_mfma_f32_16x16x32_bf16(kf1, qf[kk], s1, 0, 0, 0);
            }
            __builtin_amdgcn_s_setprio(0);

            float p00 = expsc(s0[0]), p01 = expsc(s0[1]);
            float p02 = expsc(s0[2]), p03 = expsc(s0[3]);
            float p10 = expsc(s1[0]), p11 = expsc(s1[1]);
            float p12 = expsc(s1[2]), p13 = expsc(s1[3]);
            lsum += ((p00 + p01) + (p02 + p03)) + ((p10 + p11) + (p12 + p13));
            uint32 a0 = cvtpk(p00, p01);   // W0 of tc even (keys 4q+0,1)
            uint32 a1 = cvtpk(p02, p03);   // W1 of tc even (keys 4q+2,3)
            uint32 b0 = cvtpk(p10, p11);   // W0 of tc odd
            uint32 b1 = cvtpk(p12, p13);   // W1 of tc odd
            // quads: a=[A0,A1,A2,A3], b=[B0,B1,B2,B3]
            asm("v_permlane32_swap_b32 %0, %1" : "+v"(a0), "+v"(b0));
            asm("v_permlane32_swap_b32 %0, %1" : "+v"(a1), "+v"(b1));
            // a=[A0,A1,B0,B1], b=[A2,A3,B2,B3]
            asm("v_permlane16_swap_b32 %0, %1" : "+v"(a0), "+v"(b0));
            asm("v_permlane16_swap_b32 %0, %1" : "+v"(a1), "+v"(b1));
            // a0=keys{8q,8q+1}, a1=keys{8q+2,3}, b0=keys{8q+4,5}, b1=keys{8q+6,7}
            union { uint32 u[4]; short8 v; } pu;
            pu.u[0] = a0; pu.u[1] = a1; pu.u[2] = b0; pu.u[3] = b1;
            pf[half] = pu.v;
        }

        // O += P V : A=P[m=qrow][k=key], B=V^T rows [n=dim][k=key]
        __builtin_amdgcn_s_setprio(1);
        #pragma unroll
        for (int tc = 0; tc < 4; ++tc) {
            short8 vf0 = *(const short8*)&Vc[(tc * 16 + col) * 72 + quad * 8];
            short8 vf1 = *(const short8*)&Vc[(tc * 16 + col) * 72 + 32 + quad * 8];
            accO[tc] = __builtin_amdgcn_mfma_f32_16x16x32_bf16(pf[0], vf0, accO[tc], 0, 0, 0);
            accO[tc] = __builtin_amdgcn_mfma_f32_16x16x32_bf16(pf[1], vf1, accO[tc], 0, 0, 0);
        }
        __builtin_amdgcn_s_setprio(0);

        __syncthreads();    // all waves done reading buf / writing buf^1
    }

    // reduce rowsums across quads: after this, lane holds l[qrow = lane&15]
    lsum += __shfl_xor(lsum, 16);
    lsum += __shfl_xor(lsum, 32);

    // write unnormalized fp32 partials + per-row lsum
    float* Op = split ? Op1 : Op0;
    #pragma unroll
    for (int tc = 0; tc < 4; ++tc)
        #pragma unroll
        for (int r = 0; r < 4; ++r)
            Op[(base + n0 + qbase + quad * 4 + r) * DH + tc * 16 + col] = accO[tc][r];
    if (lane < 16)
        lpart[(size_t)split * PAIRS * NN + base + n0 + qbase + lane] = lsum;
}

// ---------------------------------------------------------------------------
// Combine split-K partials: O = (X0 + X1) / (l0 + l1), bf16 out.
// One thread per 8 dims; 2048 blocks x 256 threads.
// ---------------------------------------------------------------------------
__global__ __launch_bounds__(256) void combine(
    const float* __restrict__ Op0, const float* __restrict__ Op1,
    const float* __restrict__ lpart, unsigned short* __restrict__ Ob)
{
    int g = blockIdx.x * 256 + threadIdx.x;
    int row = g >> 3;
    int d0 = (g & 7) * 8;
    const float4* a = (const float4*)(Op0 + (size_t)row * DH + d0);
    const float4* b = (const float4*)(Op1 + (size_t)row * DH + d0);
    float4 a0 = a[0], a1 = a[1], b0 = b[0], b1 = b[1];
    float inv = 1.f / (lpart[row] + lpart[(size_t)PAIRS * NN + row]);
    uint4 o;
    o.x = pack2((a0.x + b0.x) * inv, (a0.y + b0.y) * inv);
    o.y = pack2((a0.z + b0.z) * inv, (a0.w + b0.w) * inv);
    o.z = pack2((a1.x + b1.x) * inv, (a1.y + b1.y) * inv);
    o.w = pack2((a1.z + b1.z) * inv, (a1.w + b1.w) * inv);
    *(uint4*)(Ob + (size_t)row * DH + d0) = o;
}

// ---------------------------------------------------------------------------
// Output projection GEMM (unchanged this round).
// ---------------------------------------------------------------------------
__global__ __launch_bounds__(256) void out_gemm(
    const unsigned short* __restrict__ Ob,
    const unsigned short* __restrict__ wob,
    const float* __restrict__ bof,
    const uint32* __restrict__ flagp,
    void* __restrict__ outp)
{
    __shared__ unsigned short As[128 * 32];
    __shared__ unsigned short Bs[128 * 32];
    const int tid = threadIdx.x;
    const int nt = blockIdx.x >> 6, mt = blockIdx.x & 63;
    const int m0 = mt * 128, n0 = nt * 128;
    const int w = tid >> 6, lane = tid & 63, quad = lane >> 4, col = lane & 15;
    const int wr = w >> 1, wc = w & 1;
    const int fp32mode = (int)*flagp;

    f32x4 acc[4][4];
    #pragma unroll
    for (int i = 0; i < 4; ++i)
        #pragma unroll
        for (int j = 0; j < 4; ++j)
            acc[i][j] = (f32x4){0.f, 0.f, 0.f, 0.f};

    for (int kt = 0; kt < 16; ++kt) {
        int k0 = kt * 32;
        int h = k0 >> 6, koff = k0 & 63;
        __syncthreads();
        #pragma unroll
        for (int it = 0; it < 2; ++it) {
            int idx = tid + it * 256;
            int row = idx >> 2, c4 = idx & 3;
            int g = m0 + row, b = g >> 12, n = g & (NN - 1);
            unsigned short* lA = &As[(size_t)(it * 256 + w * 64) * 8];
            unsigned short* lB = &Bs[(size_t)(it * 256 + w * 64) * 8];
            gload16(Ob + ((size_t)((b << 3) + h) * NN + n) * DH + koff + c4 * 8, lA);
            gload16(wob + (size_t)(n0 + row) * DD + k0 + c4 * 8, lB);
        }
        __syncthreads();
        short8 wf[4], yf[4];
        #pragma unroll
        for (int i = 0; i < 4; ++i)
            wf[i] = *(const short8*)&Bs[(wr * 64 + i * 16 + col) * 32 + quad * 8];
        #pragma unroll
        for (int j = 0; j < 4; ++j)
            yf[j] = *(const short8*)&As[(wc * 64 + j * 16 + col) * 32 + quad * 8];
        #pragma unroll
        for (int i = 0; i < 4; ++i)
            #pragma unroll
            for (int j = 0; j < 4; ++j)
                acc[i][j] = __builtin_amdgcn_mfma_f32_16x16x32_bf16(
                    wf[i], yf[j], acc[i][j], 0, 0, 0);
    }

    #pragma unroll
    for (int i = 0; i < 4; ++i) {
        int e0 = n0 + wr * 64 + i * 16 + quad * 4;
        float4 bj = *(const float4*)(bof + e0);
        #pragma unroll
        for (int j = 0; j < 4; ++j) {
            int g = m0 + wc * 64 + j * 16 + col;
            float v0 = acc[i][j][0] + bj.x;
            float v1 = acc[i][j][1] + bj.y;
            float v2 = acc[i][j][2] + bj.z;
            float v3 = acc[i][j][3] + bj.w;
            if (fp32mode) {
                float4 o; o.x = v0; o.y = v1; o.z = v2; o.w = v3;
                *(float4*)((float*)outp + (size_t)g * DD + e0) = o;
            } else {
                uint2 o; o.x = pack2(v0, v1); o.y = pack2(v2, v3);
                *(uint2*)((unsigned short*)outp + (size_t)g * DD + e0) = o;
            }
        }
    }
}

// ---------------------------------------------------------------------------
extern "C" void kernel_launch(void* const* d_in, const int* in_sizes, int n_in,
                              void* d_out, int out_size, void* d_ws, size_t ws_size,
                              hipStream_t stream) {
    char* p = (char*)d_ws;
    uint32* flag = (uint32*)p;                  p += 256;
    unsigned short* xb  = (unsigned short*)p;   p += (size_t)BN * DD * 2;
    unsigned short* wsb = (unsigned short*)p;   p += (size_t)4 * DD * DD * 2;
    float*          bsf = (float*)p;            p += (size_t)4 * DD * 4;
    unsigned short* Qb  = (unsigned short*)p;   p += (size_t)PAIRS * NN * DH * 2;
    unsigned short* Kb  = (unsigned short*)p;   p += (size_t)PAIRS * NN * DH * 2;
    unsigned short* VTg = (unsigned short*)p;   p += (size_t)PAIRS * NN * DH * 2;
    float*          Op0 = (float*)p;            p += (size_t)PAIRS * NN * DH * 4;
    float*          Op1 = (float*)p;            p += (size_t)PAIRS * NN * DH * 4;
    float*          lpart = (float*)p;          p += (size_t)2 * PAIRS * NN * 4;
    // Ob aliases Qb: Qb is dead after attn_mfma; combine writes it, out_gemm reads it.
    unsigned short* Ob  = Qb;

    detect_dtype<<<1, 64, 0, stream>>>((const uint32*)d_in[0], flag);
    conv_x<<<BN * DD / 2048, 256, 0, stream>>>(d_in[0], xb, flag);
    conv_w<<<512, 256, 0, stream>>>(d_in[1], d_in[3], d_in[5], d_in[7], wsb, flag);
    conv_b<<<1, 256, 0, stream>>>(d_in[2], d_in[4], d_in[6], d_in[8], bsf, flag);
    qkv_gemm<<<768, 256, 0, stream>>>(xb, wsb, bsf, Qb, Kb, VTg);
    attn_mfma<<<PAIRS * 64, 512, 0, stream>>>(Qb, Kb, VTg, Op0, Op1, lpart);
    combine<<<PAIRS * NN * DH / (8 * 256), 256, 0, stream>>>(Op0, Op1, lpart, Ob);
    out_gemm<<<256, 256, 0, stream>>>(Ob, wsb + (size_t)3 * DD * DD,
                                      bsf + 3 * DD, flag, d_out);
}

// Round 7
// 216.447 us; speedup vs baseline: 1.5386x; 1.5386x over previous
//
#include <hip/hip_runtime.h>
#include <hip/hip_bf16.h>

#define NN 4096
#define DD 512
#define HH 8
#define DH 64
#define BN 8192        // total rows (B*N)
#define PAIRS 16       // B*H

typedef unsigned int uint32;
typedef __attribute__((ext_vector_type(8))) short short8;
typedef __attribute__((ext_vector_type(4))) float f32x4;

__device__ __forceinline__ unsigned short f2b(float x) {   // round-half-up to bf16
    union { float f; uint32 u; } c; c.f = x;
    return (unsigned short)((c.u + 0x8000u) >> 16);
}
__device__ __forceinline__ uint32 pack2(float lo, float hi) {
    return (uint32)f2b(lo) | ((uint32)f2b(hi) << 16);
}
__device__ __forceinline__ uint32 cvtpk(float lo, float hi) {  // packed bf16 pair, RNE
    uint32 r;
    asm("v_cvt_pk_bf16_f32 %0, %1, %2" : "=v"(r) : "v"(lo), "v"(hi));
    return r;
}
// softmax scale (1/8 * log2e) pre-folded into Q by qkv_gemm. No clamp needed.
__device__ __forceinline__ float expsc(float s) {
    return __builtin_amdgcn_exp2f(s);
}
#define QSCALE 0.18033688011112042f   // log2(e)/8

// async global->LDS, 16B per lane; LDS dest is wave-uniform base + lane*16
__device__ __forceinline__ void gload16(const void* g, void* l) {
    __builtin_amdgcn_global_load_lds(
        (const __attribute__((address_space(1))) void*)g,
        (__attribute__((address_space(3))) void*)l, 16, 0, 0);
}

// Per-wave dtype probe: every wave recomputes the flag from the first 1024
// dwords of x (L3-hot after first touch). Same sample set as the old
// detect_dtype kernel -> identical decision in every block, no cross-kernel
// dependency, no flag buffer. fp32mode=1 means input is fp32.
__device__ __forceinline__ uint32 dtype_flag_wave(const uint32* __restrict__ xw) {
    int lane = threadIdx.x & 63;
    int c = 0;
    #pragma unroll
    for (int r = 0; r < 16; ++r) {
        uint32 e = (xw[lane + r * 64] >> 7) & 0xFFu;
        if (e >= 110u && e <= 135u) c++;
    }
    c += __shfl_xor(c, 1);  c += __shfl_xor(c, 2);  c += __shfl_xor(c, 4);
    c += __shfl_xor(c, 8);  c += __shfl_xor(c, 16); c += __shfl_xor(c, 32);
    return (c < 512) ? 1u : 0u;
}

// ---------------------------------------------------------------------------
// Fused convert kernel: blocks 0..2047 convert x, 2048..2559 convert the 4
// weight matrices, block 2560 converts the 4 biases. Dtype decided per-wave.
// ---------------------------------------------------------------------------
__global__ __launch_bounds__(256) void conv_all(
    const void* __restrict__ xsrc,
    const void* w0, const void* w1, const void* w2, const void* w3,
    const void* b0, const void* b1, const void* b2, const void* b3,
    unsigned short* __restrict__ xb,
    unsigned short* __restrict__ wsb,
    float* __restrict__ bsf)
{
    const uint32 fp32mode = dtype_flag_wave((const uint32*)xsrc);
    const int bid = blockIdx.x;
    if (bid < 2048) {
        int i0 = (bid * 256 + threadIdx.x) * 8;
        if (fp32mode) {
            const float4* s = (const float4*)xsrc;
            float4 a = s[i0 >> 2], b = s[(i0 >> 2) + 1];
            uint4 o;
            o.x = pack2(a.x, a.y); o.y = pack2(a.z, a.w);
            o.z = pack2(b.x, b.y); o.w = pack2(b.z, b.w);
            *(uint4*)(xb + i0) = o;
        } else {
            *(uint4*)(xb + i0) = ((const uint4*)xsrc)[i0 >> 3];
        }
    } else if (bid < 2560) {
        int bb = bid - 2048;
        int seg = bb >> 7;
        const void* src = (seg == 0) ? w0 : (seg == 1) ? w1 : (seg == 2) ? w2 : w3;
        unsigned short* d = wsb + (size_t)seg * DD * DD;
        int i0 = ((bb & 127) * 256 + threadIdx.x) * 8;
        if (fp32mode) {
            const float4* s = (const float4*)src;
            float4 a = s[i0 >> 2], b = s[(i0 >> 2) + 1];
            uint4 o;
            o.x = pack2(a.x, a.y); o.y = pack2(a.z, a.w);
            o.z = pack2(b.x, b.y); o.w = pack2(b.z, b.w);
            *(uint4*)(d + i0) = o;
        } else {
            *(uint4*)(d + i0) = ((const uint4*)src)[i0 >> 3];
        }
    } else {
        const void* sl[4] = { b0, b1, b2, b3 };
        #pragma unroll
        for (int m = 0; m < 4; ++m) {
            #pragma unroll
            for (int j = 0; j < 2; ++j) {
                int i = threadIdx.x * 2 + j;
                float v;
                if (fp32mode) v = ((const float*)sl[m])[i];
                else {
                    union { uint32 u; float f; } c;
                    c.u = ((uint32)((const unsigned short*)sl[m])[i]) << 16;
                    v = c.f;
                }
                bsf[m * DD + i] = v;
            }
        }
    }
}

// ---------------------------------------------------------------------------
// QKV projection GEMM (unchanged from round 5): m97-style staging, linear
// LDS, global_load_lds. Q pre-scaled by log2(e)/8.
// ---------------------------------------------------------------------------
__global__ __launch_bounds__(256) void qkv_gemm(
    const unsigned short* __restrict__ xb,
    const unsigned short* __restrict__ wsb,
    const float* __restrict__ bsf,
    unsigned short* __restrict__ Qb, unsigned short* __restrict__ Kb,
    unsigned short* __restrict__ VTg)
{
    __shared__ unsigned short As[128 * 32];
    __shared__ unsigned short Bs[128 * 32];
    const int tid = threadIdx.x;
    const int mat = blockIdx.x >> 8;
    const int rem = blockIdx.x & 255;
    const int nt = rem >> 6, mt = rem & 63;
    const int m0 = mt * 128, n0 = nt * 128;
    const int w = tid >> 6, lane = tid & 63, quad = lane >> 4, col = lane & 15;
    const int wr = w >> 1, wc = w & 1;
    const unsigned short* wm = wsb + (size_t)mat * DD * DD;
    const bool qk = (mat < 2);

    f32x4 acc[4][4];
    #pragma unroll
    for (int i = 0; i < 4; ++i)
        #pragma unroll
        for (int j = 0; j < 4; ++j)
            acc[i][j] = (f32x4){0.f, 0.f, 0.f, 0.f};

    for (int kt = 0; kt < 16; ++kt) {
        int k0 = kt * 32;
        __syncthreads();
        #pragma unroll
        for (int it = 0; it < 2; ++it) {
            int idx = tid + it * 256;
            int row = idx >> 2, c4 = idx & 3;
            unsigned short* lA = &As[(size_t)(it * 256 + w * 64) * 8];
            unsigned short* lB = &Bs[(size_t)(it * 256 + w * 64) * 8];
            gload16(xb + (size_t)(m0 + row) * DD + k0 + c4 * 8, lA);
            gload16(wm + (size_t)(n0 + row) * DD + k0 + c4 * 8, lB);
        }
        __syncthreads();
        if (qk) {
            short8 wf[4], xf[4];
            #pragma unroll
            for (int i = 0; i < 4; ++i)
                wf[i] = *(const short8*)&Bs[(wr * 64 + i * 16 + col) * 32 + quad * 8];
            #pragma unroll
            for (int j = 0; j < 4; ++j)
                xf[j] = *(const short8*)&As[(wc * 64 + j * 16 + col) * 32 + quad * 8];
            #pragma unroll
            for (int i = 0; i < 4; ++i)
                #pragma unroll
                for (int j = 0; j < 4; ++j)
                    acc[i][j] = __builtin_amdgcn_mfma_f32_16x16x32_bf16(
                        wf[i], xf[j], acc[i][j], 0, 0, 0);
        } else {
            short8 xf[4], wf[4];
            #pragma unroll
            for (int i = 0; i < 4; ++i)
                xf[i] = *(const short8*)&As[(wr * 64 + i * 16 + col) * 32 + quad * 8];
            #pragma unroll
            for (int j = 0; j < 4; ++j)
                wf[j] = *(const short8*)&Bs[(wc * 64 + j * 16 + col) * 32 + quad * 8];
            #pragma unroll
            for (int i = 0; i < 4; ++i)
                #pragma unroll
                for (int j = 0; j < 4; ++j)
                    acc[i][j] = __builtin_amdgcn_mfma_f32_16x16x32_bf16(
                        xf[i], wf[j], acc[i][j], 0, 0, 0);
        }
    }

    if (qk) {
        unsigned short* Om = (mat == 0) ? Qb : Kb;
        const float qs = (mat == 0) ? QSCALE : 1.0f;
        #pragma unroll
        for (int i = 0; i < 4; ++i) {
            int e0 = n0 + wr * 64 + i * 16 + quad * 4;
            float4 bj = *(const float4*)(bsf + mat * DD + e0);
            int h = e0 >> 6, jj0 = e0 & 63;
            #pragma unroll
            for (int j = 0; j < 4; ++j) {
                int g = m0 + wc * 64 + j * 16 + col;
                int b = g >> 12, n = g & (NN - 1);
                uint32 lo = pack2((acc[i][j][0] + bj.x) * qs, (acc[i][j][1] + bj.y) * qs);
                uint32 hi = pack2((acc[i][j][2] + bj.z) * qs, (acc[i][j][3] + bj.w) * qs);
                uint2 v; v.x = lo; v.y = hi;
                *(uint2*)(Om + ((size_t)((b << 3) + h) * NN + n) * DH + jj0) = v;
            }
        }
    } else {
        #pragma unroll
        for (int j = 0; j < 4; ++j) {
            int e = n0 + wc * 64 + j * 16 + col;
            float bj = bsf[2 * DD + e];
            int h = e >> 6, jj = e & 63;
            #pragma unroll
            for (int i = 0; i < 4; ++i) {
                int g0 = m0 + wr * 64 + i * 16 + quad * 4;
                int b = g0 >> 12, n = g0 & (NN - 1);
                uint32 lo = pack2(acc[i][j][0] + bj, acc[i][j][1] + bj);
                uint32 hi = pack2(acc[i][j][2] + bj, acc[i][j][3] + bj);
                uint2 v; v.x = lo; v.y = hi;
                *(uint2*)(VTg + ((size_t)((b << 3) + h) * DH + jj) * NN + n) = v;
            }
        }
    }
}

// ---------------------------------------------------------------------------
// MFMA flash attention (round-5 version, 97us verified): 512 thr, QBLK=128,
// 8 waves, double-buffered K/V, 1 barrier/iter, reg prefetch, in-register P
// redistribution via permlane32/16_swap, exp2 direct (no clamp).
// ---------------------------------------------------------------------------
__global__ __launch_bounds__(512, 4) void attn_mfma(
    const unsigned short* __restrict__ Qb,
    const unsigned short* __restrict__ Kb,
    const unsigned short* __restrict__ VTg,
    unsigned short* __restrict__ Ob)
{
    __shared__ unsigned short Kt[2][64 * 72];    // [key][dim],  pad 64->72
    __shared__ unsigned short Vt[2][64 * 72];    // [dim][key],  pad 64->72

    const int tid  = threadIdx.x;
    const int w    = tid >> 6;
    const int lane = tid & 63;
    const int quad = lane >> 4;
    const int col  = lane & 15;
    const int pair = blockIdx.x >> 5;
    const int chunk = blockIdx.x & 31;
    const size_t base = (size_t)pair * NN;
    const int n0 = chunk * 128;
    const int qbase = w * 16;

    // Q A-fragments for this wave's 16 rows: lane&15 = qrow, regs = dim
    short8 qf[2];
    #pragma unroll
    for (int kk = 0; kk < 2; ++kk)
        qf[kk] = *(const short8*)(Qb +
            (base + n0 + qbase + col) * DH + kk * 32 + quad * 8);

    f32x4 accO[4];
    #pragma unroll
    for (int tc = 0; tc < 4; ++tc) accO[tc] = (f32x4){0.f, 0.f, 0.f, 0.f};
    float lsum = 0.f;

    const int skey = tid >> 3;      // 0..63 (key for K stage, dim for V stage)
    const int sc8  = (tid & 7) * 8;
    const unsigned short* Kg = Kb + base * DH;
    const unsigned short* Vg = VTg + (size_t)pair * DH * NN;

    // prologue: tile 0 -> LDS buf0; tile 1 -> regs
    uint4 kreg = *(const uint4*)(Kg + (size_t)skey * DH + sc8);
    uint4 vreg = *(const uint4*)(Vg + (size_t)skey * NN + sc8);
    *(uint4*)&Kt[0][skey * 72 + sc8] = kreg;
    *(uint4*)&Vt[0][skey * 72 + sc8] = vreg;
    kreg = *(const uint4*)(Kg + (size_t)(64 + skey) * DH + sc8);
    vreg = *(const uint4*)(Vg + (size_t)skey * NN + 64 + sc8);
    __syncthreads();

    for (int kt = 0; kt < NN / 64; ++kt) {
        const int buf = kt & 1;
        if (kt + 1 < NN / 64) {
            // stage next tile into the other buffer; prefetch tile kt+2
            *(uint4*)&Kt[buf ^ 1][skey * 72 + sc8] = kreg;
            *(uint4*)&Vt[buf ^ 1][skey * 72 + sc8] = vreg;
            int tn = (kt + 2 < NN / 64) ? kt + 2 : 0;   // clamp (dummy, cached)
            kreg = *(const uint4*)(Kg + (size_t)(tn * 64 + skey) * DH + sc8);
            vreg = *(const uint4*)(Vg + (size_t)skey * NN + tn * 64 + sc8);
        }
        const unsigned short* Kc = &Kt[buf][0];
        const unsigned short* Vc = &Vt[buf][0];

        // per 32-key half: S^T via MFMA (2 tiles interleaved), exp, permlane
        short8 pf[2];
        #pragma unroll
        for (int half = 0; half < 2; ++half) {
            f32x4 s0 = (f32x4){0.f, 0.f, 0.f, 0.f};
            f32x4 s1 = (f32x4){0.f, 0.f, 0.f, 0.f};
            __builtin_amdgcn_s_setprio(1);
            #pragma unroll
            for (int kk = 0; kk < 2; ++kk) {
                short8 kf0 = *(const short8*)&Kc[((half * 2 + 0) * 16 + col) * 72 + kk * 32 + quad * 8];
                short8 kf1 = *(const short8*)&Kc[((half * 2 + 1) * 16 + col) * 72 + kk * 32 + quad * 8];
                s0 = __builtin_amdgcn_mfma_f32_16x16x32_bf16(kf0, qf[kk], s0, 0, 0, 0);
                s1 = __builtin_amdgcn_mfma_f32_16x16x32_bf16(kf1, qf[kk], s1, 0, 0, 0);
            }
            __builtin_amdgcn_s_setprio(0);

            float p00 = expsc(s0[0]), p01 = expsc(s0[1]);
            float p02 = expsc(s0[2]), p03 = expsc(s0[3]);
            float p10 = expsc(s1[0]), p11 = expsc(s1[1]);
            float p12 = expsc(s1[2]), p13 = expsc(s1[3]);
            lsum += ((p00 + p01) + (p02 + p03)) + ((p10 + p11) + (p12 + p13));
            uint32 a0 = cvtpk(p00, p01);   // W0 of tc even (keys 4q+0,1)
            uint32 a1 = cvtpk(p02, p03);   // W1 of tc even (keys 4q+2,3)
            uint32 b0 = cvtpk(p10, p11);   // W0 of tc odd
            uint32 b1 = cvtpk(p12, p13);   // W1 of tc odd
            // quads: a=[A0,A1,A2,A3], b=[B0,B1,B2,B3]
            asm("v_permlane32_swap_b32 %0, %1" : "+v"(a0), "+v"(b0));
            asm("v_permlane32_swap_b32 %0, %1" : "+v"(a1), "+v"(b1));
            // a=[A0,A1,B0,B1], b=[A2,A3,B2,B3]
            asm("v_permlane16_swap_b32 %0, %1" : "+v"(a0), "+v"(b0));
            asm("v_permlane16_swap_b32 %0, %1" : "+v"(a1), "+v"(b1));
            // a0=keys{8q,8q+1}, a1=keys{8q+2,3}, b0=keys{8q+4,5}, b1=keys{8q+6,7}
            union { uint32 u[4]; short8 v; } pu;
            pu.u[0] = a0; pu.u[1] = a1; pu.u[2] = b0; pu.u[3] = b1;
            pf[half] = pu.v;
        }

        // O += P V : A=P[m=qrow][k=key], B=V^T rows [n=dim][k=key]
        __builtin_amdgcn_s_setprio(1);
        #pragma unroll
        for (int tc = 0; tc < 4; ++tc) {
            short8 vf0 = *(const short8*)&Vc[(tc * 16 + col) * 72 + quad * 8];
            short8 vf1 = *(const short8*)&Vc[(tc * 16 + col) * 72 + 32 + quad * 8];
            accO[tc] = __builtin_amdgcn_mfma_f32_16x16x32_bf16(pf[0], vf0, accO[tc], 0, 0, 0);
            accO[tc] = __builtin_amdgcn_mfma_f32_16x16x32_bf16(pf[1], vf1, accO[tc], 0, 0, 0);
        }
        __builtin_amdgcn_s_setprio(0);

        __syncthreads();    // all waves done reading buf / writing buf^1
    }

    // reduce rowsums across quads: after this, lane holds l[qrow = lane&15]
    lsum += __shfl_xor(lsum, 16);
    lsum += __shfl_xor(lsum, 32);

    // epilogue: need l for qrow = quad*4+r
    float inv[4];
    #pragma unroll
    for (int r = 0; r < 4; ++r)
        inv[r] = 1.f / __shfl(lsum, quad * 4 + r);

    #pragma unroll
    for (int tc = 0; tc < 4; ++tc)
        #pragma unroll
        for (int r = 0; r < 4; ++r) {
            float v = accO[tc][r] * inv[r];
            Ob[(base + n0 + qbase + quad * 4 + r) * DH + tc * 16 + col] = f2b(v);
        }
}

// ---------------------------------------------------------------------------
// Output projection GEMM (round-5 structure; flag recomputed per-wave from x).
// ---------------------------------------------------------------------------
__global__ __launch_bounds__(256) void out_gemm(
    const unsigned short* __restrict__ Ob,
    const unsigned short* __restrict__ wob,
    const float* __restrict__ bof,
    const void* __restrict__ xsrc,
    void* __restrict__ outp)
{
    __shared__ unsigned short As[128 * 32];
    __shared__ unsigned short Bs[128 * 32];
    const int tid = threadIdx.x;
    const int nt = blockIdx.x >> 6, mt = blockIdx.x & 63;
    const int m0 = mt * 128, n0 = nt * 128;
    const int w = tid >> 6, lane = tid & 63, quad = lane >> 4, col = lane & 15;
    const int wr = w >> 1, wc = w & 1;
    const int fp32mode = (int)dtype_flag_wave((const uint32*)xsrc);

    f32x4 acc[4][4];
    #pragma unroll
    for (int i = 0; i < 4; ++i)
        #pragma unroll
        for (int j = 0; j < 4; ++j)
            acc[i][j] = (f32x4){0.f, 0.f, 0.f, 0.f};

    for (int kt = 0; kt < 16; ++kt) {
        int k0 = kt * 32;
        int h = k0 >> 6, koff = k0 & 63;
        __syncthreads();
        #pragma unroll
        for (int it = 0; it < 2; ++it) {
            int idx = tid + it * 256;
            int row = idx >> 2, c4 = idx & 3;
            int g = m0 + row, b = g >> 12, n = g & (NN - 1);
            unsigned short* lA = &As[(size_t)(it * 256 + w * 64) * 8];
            unsigned short* lB = &Bs[(size_t)(it * 256 + w * 64) * 8];
            gload16(Ob + ((size_t)((b << 3) + h) * NN + n) * DH + koff + c4 * 8, lA);
            gload16(wob + (size_t)(n0 + row) * DD + k0 + c4 * 8, lB);
        }
        __syncthreads();
        short8 wf[4], yf[4];
        #pragma unroll
        for (int i = 0; i < 4; ++i)
            wf[i] = *(const short8*)&Bs[(wr * 64 + i * 16 + col) * 32 + quad * 8];
        #pragma unroll
        for (int j = 0; j < 4; ++j)
            yf[j] = *(const short8*)&As[(wc * 64 + j * 16 + col) * 32 + quad * 8];
        #pragma unroll
        for (int i = 0; i < 4; ++i)
            #pragma unroll
            for (int j = 0; j < 4; ++j)
                acc[i][j] = __builtin_amdgcn_mfma_f32_16x16x32_bf16(
                    wf[i], yf[j], acc[i][j], 0, 0, 0);
    }

    #pragma unroll
    for (int i = 0; i < 4; ++i) {
        int e0 = n0 + wr * 64 + i * 16 + quad * 4;
        float4 bj = *(const float4*)(bof + e0);
        #pragma unroll
        for (int j = 0; j < 4; ++j) {
            int g = m0 + wc * 64 + j * 16 + col;
            float v0 = acc[i][j][0] + bj.x;
            float v1 = acc[i][j][1] + bj.y;
            float v2 = acc[i][j][2] + bj.z;
            float v3 = acc[i][j][3] + bj.w;
            if (fp32mode) {
                float4 o; o.x = v0; o.y = v1; o.z = v2; o.w = v3;
                *(float4*)((float*)outp + (size_t)g * DD + e0) = o;
            } else {
                uint2 o; o.x = pack2(v0, v1); o.y = pack2(v2, v3);
                *(uint2*)((unsigned short*)outp + (size_t)g * DD + e0) = o;
            }
        }
    }
}

// ---------------------------------------------------------------------------
extern "C" void kernel_launch(void* const* d_in, const int* in_sizes, int n_in,
                              void* d_out, int out_size, void* d_ws, size_t ws_size,
                              hipStream_t stream) {
    char* p = (char*)d_ws;
    unsigned short* xb  = (unsigned short*)p;   p += (size_t)BN * DD * 2;
    unsigned short* wsb = (unsigned short*)p;   p += (size_t)4 * DD * DD * 2;
    float*          bsf = (float*)p;            p += (size_t)4 * DD * 4;
    unsigned short* Qb  = (unsigned short*)p;   p += (size_t)PAIRS * NN * DH * 2;
    unsigned short* Kb  = (unsigned short*)p;   p += (size_t)PAIRS * NN * DH * 2;
    unsigned short* VTg = (unsigned short*)p;   p += (size_t)PAIRS * NN * DH * 2;
    unsigned short* Ob  = (unsigned short*)p;   p += (size_t)PAIRS * NN * DH * 2;

    conv_all<<<2561, 256, 0, stream>>>(d_in[0],
                                       d_in[1], d_in[3], d_in[5], d_in[7],
                                       d_in[2], d_in[4], d_in[6], d_in[8],
                                       xb, wsb, bsf);
    qkv_gemm<<<768, 256, 0, stream>>>(xb, wsb, bsf, Qb, Kb, VTg);
    attn_mfma<<<PAIRS * 32, 512, 0, stream>>>(Qb, Kb, VTg, Ob);
    out_gemm<<<256, 256, 0, stream>>>(Ob, wsb + (size_t)3 * DD * DD,
                                      bsf + 3 * DD, d_in[0], d_out);
}